// Round 1
// baseline (210.888 us; speedup 1.0000x reference)
//
#include <hip/hip_runtime.h>

#define N_NODES 50000
#define N_EDGES 800000
#define D 128

// ---------------- workspace layout (bytes) ----------------
// deg[i]   : int   count of incoming edges (without self loop)
// cur[i]   : int   fill cursor for CSR build
// offs[i]  : int   exclusive prefix of deg
// inv[i]   : float rsqrt(deg+1)
// part[]   : int   per-block partial sums for scan
// csr[]    : int   src node id per CSR slot (grouped by dst)
// XW[]     : float X @ W  [N, 128]
static const size_t OFF_DEG  = 0;
static const size_t OFF_CUR  = 200192;            // 50000*4 -> pad 512
static const size_t OFF_OFFS = 400384;
static const size_t OFF_INV  = 600576;
static const size_t OFF_PART = 800768;
static const size_t OFF_CSR  = 801280;            // 800000*4 = 3.2MB
static const size_t OFF_XW   = 4001280;           // 50000*128*4 = 25.6MB
// total ws needed: 29,601,280 bytes

#define SCAN_B 1024
#define SCAN_NB ((N_NODES + SCAN_B - 1) / SCAN_B)   // 49

__global__ void k_degree(const int* __restrict__ dst, int* __restrict__ deg) {
    int e = blockIdx.x * blockDim.x + threadIdx.x;
    if (e < N_EDGES) atomicAdd(&deg[dst[e]], 1);
}

__global__ void k_scan1(const int* __restrict__ deg, int* __restrict__ part) {
    int t = threadIdx.x;
    int i = blockIdx.x * SCAN_B + t;
    int v = (i < N_NODES) ? deg[i] : 0;
    #pragma unroll
    for (int off = 32; off >= 1; off >>= 1) v += __shfl_down(v, off, 64);
    __shared__ int ws[16];
    int wid = t >> 6, lane = t & 63;
    if (lane == 0) ws[wid] = v;
    __syncthreads();
    if (t < 64) {
        int s = (t < 16) ? ws[t] : 0;
        #pragma unroll
        for (int off = 8; off >= 1; off >>= 1) s += __shfl_down(s, off, 64);
        if (t == 0) part[blockIdx.x] = s;
    }
}

__global__ void k_scan2(int* part) {
    int lane = threadIdx.x;  // one wave of 64
    int orig = (lane < SCAN_NB) ? part[lane] : 0;
    int v = orig;
    #pragma unroll
    for (int d = 1; d < 64; d <<= 1) {
        int u = __shfl_up(v, d, 64);
        if (lane >= d) v += u;
    }
    if (lane < SCAN_NB) part[lane] = v - orig;  // exclusive
}

__global__ void k_scan3(const int* __restrict__ deg, const int* __restrict__ part,
                        int* __restrict__ offs, float* __restrict__ inv) {
    __shared__ int sd[SCAN_B];
    int t = threadIdx.x;
    int i = blockIdx.x * SCAN_B + t;
    int v = (i < N_NODES) ? deg[i] : 0;
    sd[t] = v;
    __syncthreads();
    for (int off = 1; off < SCAN_B; off <<= 1) {
        int add = (t >= off) ? sd[t - off] : 0;
        __syncthreads();
        sd[t] += add;
        __syncthreads();
    }
    if (i < N_NODES) {
        int incl = sd[t];
        offs[i] = incl - v + part[blockIdx.x];
        inv[i] = rsqrtf((float)v + 1.0f);
    }
}

__global__ void k_fill(const int* __restrict__ src, const int* __restrict__ dst,
                       const int* __restrict__ offs, int* __restrict__ cur,
                       int* __restrict__ csr) {
    int e = blockIdx.x * blockDim.x + threadIdx.x;
    if (e < N_EDGES) {
        int d = dst[e];
        int p = atomicAdd(&cur[d], 1);
        csr[offs[d] + p] = src[e];
    }
}

// ---------------- XW = X @ W (f32 vector GEMM) ----------------
// Block: 256 threads, tile = 64 rows x 128 cols.
// W fully staged in LDS (64KB). X tile transposed in LDS (pad 68 to dodge
// worst bank conflicts). Thread (rg = t>>5, c4 = t&31) computes 8 rows x 4 cols.
#define GR 64
__global__ __launch_bounds__(256) void k_gemm(const float* __restrict__ X,
                                              const float* __restrict__ W,
                                              float* __restrict__ XW) {
    __shared__ float Wl[D * D];       // 64KB
    __shared__ float Xt[D * 68];      // 34.8KB, Xt[k*68 + r]
    int t = threadIdx.x;

    const float4* W4 = (const float4*)W;
    float4* Wl4 = (float4*)Wl;
    #pragma unroll
    for (int i = 0; i < 16; ++i) Wl4[t + i * 256] = W4[t + i * 256];

    int r0b = blockIdx.x * GR;
    int k4 = t & 31;
    int rq = t >> 5;
    #pragma unroll
    for (int l = 0; l < 8; ++l) {
        int r = rq * 8 + l;
        int row = r0b + r;
        float4 xv = make_float4(0.f, 0.f, 0.f, 0.f);
        if (row < N_NODES) xv = *(const float4*)&X[row * D + k4 * 4];
        Xt[(k4 * 4 + 0) * 68 + r] = xv.x;
        Xt[(k4 * 4 + 1) * 68 + r] = xv.y;
        Xt[(k4 * 4 + 2) * 68 + r] = xv.z;
        Xt[(k4 * 4 + 3) * 68 + r] = xv.w;
    }
    __syncthreads();

    int c4 = t & 31, rg = t >> 5;
    float4 acc[8];
    #pragma unroll
    for (int i = 0; i < 8; ++i) acc[i] = make_float4(0.f, 0.f, 0.f, 0.f);

    #pragma unroll 4
    for (int k = 0; k < D; ++k) {
        float4 wv = *(const float4*)&Wl[k * D + c4 * 4];
        const float* xr = &Xt[k * 68 + rg * 8];
        float4 xa = *(const float4*)xr;
        float4 xb = *(const float4*)(xr + 4);
        float xs0 = xa.x, xs1 = xa.y, xs2 = xa.z, xs3 = xa.w;
        float xs4 = xb.x, xs5 = xb.y, xs6 = xb.z, xs7 = xb.w;
        float xs[8] = {xs0, xs1, xs2, xs3, xs4, xs5, xs6, xs7};
        #pragma unroll
        for (int i = 0; i < 8; ++i) {
            acc[i].x += wv.x * xs[i];
            acc[i].y += wv.y * xs[i];
            acc[i].z += wv.z * xs[i];
            acc[i].w += wv.w * xs[i];
        }
    }

    #pragma unroll
    for (int i = 0; i < 8; ++i) {
        int row = r0b + rg * 8 + i;
        if (row < N_NODES) *(float4*)&XW[row * D + c4 * 4] = acc[i];
    }
}

// ---------------- aggregate: out[d] = sum_e XW[src_e]*norm + XW[d]*inv^2 ----
// 32 lanes per node (each lane owns a float4 of the 128-wide row).
__global__ __launch_bounds__(256) void k_agg(const float* __restrict__ XW,
                                             const int* __restrict__ csr,
                                             const int* __restrict__ offs,
                                             const int* __restrict__ deg,
                                             const float* __restrict__ inv,
                                             float* __restrict__ out) {
    int node = blockIdx.x * 8 + (threadIdx.x >> 5);
    if (node >= N_NODES) return;
    int l32 = threadIdx.x & 31;
    int start = offs[node];
    int cnt = deg[node];
    float invd = inv[node];

    const float4* xw4 = (const float4*)XW;
    float4 self = xw4[node * 32 + l32];
    float sl = invd * invd;
    float4 acc;
    acc.x = self.x * sl; acc.y = self.y * sl;
    acc.z = self.z * sl; acc.w = self.w * sl;

    for (int e = 0; e < cnt; ++e) {
        int s = csr[start + e];
        float nrm = invd * inv[s];
        float4 v = xw4[s * 32 + l32];
        acc.x += v.x * nrm; acc.y += v.y * nrm;
        acc.z += v.z * nrm; acc.w += v.w * nrm;
    }
    ((float4*)out)[node * 32 + l32] = acc;
}

extern "C" void kernel_launch(void* const* d_in, const int* in_sizes, int n_in,
                              void* d_out, int out_size, void* d_ws, size_t ws_size,
                              hipStream_t stream) {
    const float* X = (const float*)d_in[0];
    const float* W = (const float*)d_in[1];
    const int* esrc = (const int*)d_in[2];
    const int* edst = (const int*)d_in[3];
    float* out = (float*)d_out;

    char* ws = (char*)d_ws;
    int* deg = (int*)(ws + OFF_DEG);
    int* cur = (int*)(ws + OFF_CUR);
    int* offs = (int*)(ws + OFF_OFFS);
    float* inv = (float*)(ws + OFF_INV);
    int* part = (int*)(ws + OFF_PART);
    int* csr = (int*)(ws + OFF_CSR);
    float* XW = (float*)(ws + OFF_XW);

    // zero deg + cur (contiguous region)
    hipMemsetAsync(ws + OFF_DEG, 0, OFF_OFFS - OFF_DEG, stream);

    int eb = (N_EDGES + 255) / 256;
    k_degree<<<eb, 256, 0, stream>>>(edst, deg);
    k_scan1<<<SCAN_NB, SCAN_B, 0, stream>>>(deg, part);
    k_scan2<<<1, 64, 0, stream>>>(part);
    k_scan3<<<SCAN_NB, SCAN_B, 0, stream>>>(deg, part, offs, inv);
    k_fill<<<eb, 256, 0, stream>>>(esrc, edst, offs, cur, csr);

    int gb = (N_NODES + GR - 1) / GR;   // 782
    k_gemm<<<gb, 256, 0, stream>>>(X, W, XW);

    int ab = (N_NODES + 7) / 8;         // 6250
    k_agg<<<ab, 256, 0, stream>>>(XW, csr, offs, deg, inv, out);
}

// Round 2
// 149.777 us; speedup vs baseline: 1.4080x; 1.4080x over previous
//
#include <hip/hip_runtime.h>

#define N_NODES 50000
#define N_EDGES 800000
#define D 128

typedef __attribute__((ext_vector_type(8))) short bf16x8;
typedef __attribute__((ext_vector_type(4))) float f32x4;

// ---------------- workspace layout (bytes) ----------------
static const size_t OFF_DEG  = 0;          // int[50000]
static const size_t OFF_CUR  = 200192;     // int[50000]
static const size_t OFF_OFFS = 400384;     // int[50000]
static const size_t OFF_INV  = 600576;     // float[50000]
static const size_t OFF_PART = 800768;     // int[49]
static const size_t OFF_WT   = 801280;     // ushort[128*128] = 32KB (W^T bf16, [n][k])
static const size_t OFF_CSR  = 834048;     // int[800000]
static const size_t OFF_XWB  = 4034048;    // ushort[50000*128] bf16
// total: 16,834,048 bytes

#define SCAN_B 1024
#define SCAN_NB ((N_NODES + SCAN_B - 1) / SCAN_B)   // 49

__device__ __forceinline__ unsigned short f2bf(float f) {
    unsigned int u = __float_as_uint(f);
    unsigned int r = (u + 0x7fffu + ((u >> 16) & 1u)) >> 16;   // RNE
    return (unsigned short)r;
}
__device__ __forceinline__ float bflo(unsigned int u) { return __uint_as_float(u << 16); }
__device__ __forceinline__ float bfhi(unsigned int u) { return __uint_as_float(u & 0xffff0000u); }

__global__ void k_degree(const int* __restrict__ dst, int* __restrict__ deg) {
    int e = blockIdx.x * blockDim.x + threadIdx.x;
    if (e < N_EDGES) atomicAdd(&deg[dst[e]], 1);
}

__global__ void k_scan1(const int* __restrict__ deg, int* __restrict__ part) {
    int t = threadIdx.x;
    int i = blockIdx.x * SCAN_B + t;
    int v = (i < N_NODES) ? deg[i] : 0;
    #pragma unroll
    for (int off = 32; off >= 1; off >>= 1) v += __shfl_down(v, off, 64);
    __shared__ int ws[16];
    int wid = t >> 6, lane = t & 63;
    if (lane == 0) ws[wid] = v;
    __syncthreads();
    if (t < 64) {
        int s = (t < 16) ? ws[t] : 0;
        #pragma unroll
        for (int off = 8; off >= 1; off >>= 1) s += __shfl_down(s, off, 64);
        if (t == 0) part[blockIdx.x] = s;
    }
}

__global__ void k_scan2(int* part) {
    int lane = threadIdx.x;  // one wave
    int orig = (lane < SCAN_NB) ? part[lane] : 0;
    int v = orig;
    #pragma unroll
    for (int d = 1; d < 64; d <<= 1) {
        int u = __shfl_up(v, d, 64);
        if (lane >= d) v += u;
    }
    if (lane < SCAN_NB) part[lane] = v - orig;  // exclusive
}

__global__ void k_scan3(const int* __restrict__ deg, const int* __restrict__ part,
                        int* __restrict__ offs, float* __restrict__ inv) {
    int t = threadIdx.x;
    int i = blockIdx.x * SCAN_B + t;
    int v = (i < N_NODES) ? deg[i] : 0;
    // wave-inclusive scan
    int s = v;
    #pragma unroll
    for (int d = 1; d < 64; d <<= 1) {
        int u = __shfl_up(s, d, 64);
        if ((t & 63) >= d) s += u;
    }
    __shared__ int wsum[16];
    if ((t & 63) == 63) wsum[t >> 6] = s;
    __syncthreads();
    if (t < 64) {
        int val = (t < 16) ? wsum[t] : 0;
        int sc = val;
        #pragma unroll
        for (int d = 1; d < 16; d <<= 1) {
            int u = __shfl_up(sc, d, 64);
            if (t >= d) sc += u;
        }
        if (t < 16) wsum[t] = sc - val;  // exclusive over waves
    }
    __syncthreads();
    if (i < N_NODES) {
        int excl = s - v + wsum[t >> 6] + part[blockIdx.x];
        offs[i] = excl;
        inv[i] = rsqrtf((float)v + 1.0f);
    }
}

__global__ void k_fill(const int* __restrict__ src, const int* __restrict__ dst,
                       const int* __restrict__ offs, int* __restrict__ cur,
                       int* __restrict__ csr) {
    int e = blockIdx.x * blockDim.x + threadIdx.x;
    if (e < N_EDGES) {
        int d = dst[e];
        int p = atomicAdd(&cur[d], 1);
        csr[offs[d] + p] = src[e];
    }
}

// ---- Wt[n][k] = bf16(W[k][n]) : tiny one-time transpose+convert ----
__global__ void k_convW(const float* __restrict__ W, unsigned short* __restrict__ Wt) {
    int n = blockIdx.x;          // 128 blocks
    int k = threadIdx.x;         // 128 threads
    Wt[n * D + k] = f2bf(W[k * D + n]);
}

// ---------------- XW(bf16) = X @ W via MFMA 16x16x32 bf16 ----------------
// Block 256 (4 waves), tile 64 rows x 128 cols. XOR-swizzled LDS (T2).
#define BM 64
__global__ __launch_bounds__(256) void k_gemm(const float* __restrict__ X,
                                              const unsigned short* __restrict__ Wt,
                                              unsigned short* __restrict__ XWb) {
    __shared__ unsigned short sA[BM * D];    // 16KB, [row][k] swizzled
    __shared__ unsigned short sB[D * D];     // 32KB, [n][k] swizzled
    int t = threadIdx.x;
    int r0 = blockIdx.x * BM;

    // stage B (Wt) : 8 passes x uint4 (8 bf16)
    #pragma unroll
    for (int p = 0; p < 8; ++p) {
        int e = p * 2048 + t * 8;
        int n = e >> 7, k = e & 127;
        uint4 v = *(const uint4*)&Wt[e];
        int idx = n * D + (((k >> 3) ^ (n & 7)) << 3);
        *(uint4*)&sB[idx] = v;
    }
    // stage A (X tile, f32 -> bf16) : 8 passes x float4
    #pragma unroll
    for (int p = 0; p < 8; ++p) {
        int e = p * 1024 + t * 4;
        int r = e >> 7, c = e & 127;
        int row = r0 + r;
        float4 xv = make_float4(0.f, 0.f, 0.f, 0.f);
        if (row < N_NODES) xv = *(const float4*)&X[row * D + c];
        ushort4 bv;
        bv.x = f2bf(xv.x); bv.y = f2bf(xv.y); bv.z = f2bf(xv.z); bv.w = f2bf(xv.w);
        int idx = r * D + (((c >> 3) ^ (r & 7)) << 3) + (c & 7);
        *(ushort4*)&sA[idx] = bv;
    }
    __syncthreads();

    int w = t >> 6, l = t & 63;
    int arow = w * 16 + (l & 15);
    f32x4 acc[8];
    #pragma unroll
    for (int i = 0; i < 8; ++i) acc[i] = (f32x4){0.f, 0.f, 0.f, 0.f};

    #pragma unroll
    for (int kk = 0; kk < 4; ++kk) {
        int g = kk * 4 + (l >> 4);
        bf16x8 a = *(bf16x8*)&sA[arow * D + ((g ^ (arow & 7)) << 3)];
        #pragma unroll
        for (int nt = 0; nt < 8; ++nt) {
            int nrow = nt * 16 + (l & 15);
            bf16x8 b = *(bf16x8*)&sB[nrow * D + ((g ^ (nrow & 7)) << 3)];
            acc[nt] = __builtin_amdgcn_mfma_f32_16x16x32_bf16(a, b, acc[nt], 0, 0, 0);
        }
    }

    // epilogue: D[col=l&15][row=(l>>4)*4+reg]
    #pragma unroll
    for (int nt = 0; nt < 8; ++nt) {
        #pragma unroll
        for (int r = 0; r < 4; ++r) {
            int m = r0 + w * 16 + (l >> 4) * 4 + r;
            if (m < N_NODES) XWb[m * D + nt * 16 + (l & 15)] = f2bf(acc[nt][r]);
        }
    }
}

// ---------------- aggregate (bf16 gather, f32 out) ----------------
// One wave per node; 4 edge-slots x 16 lanes (16B bf16 chunk each).
__global__ __launch_bounds__(256) void k_agg(const unsigned short* __restrict__ XWb,
                                             const int* __restrict__ csr,
                                             const int* __restrict__ offs,
                                             const int* __restrict__ deg,
                                             const float* __restrict__ inv,
                                             float* __restrict__ out) {
    int node = blockIdx.x * 4 + (threadIdx.x >> 6);
    if (node >= N_NODES) return;
    int l = threadIdx.x & 63;
    int eg = l >> 4;        // edge slot 0..3
    int cl = l & 15;        // 16B chunk (8 bf16)

    int start = offs[node];
    int cnt = deg[node];
    float invd = inv[node];

    float acc[8];
    #pragma unroll
    for (int j = 0; j < 8; ++j) acc[j] = 0.f;

    if (eg == 0) {  // self term once
        float sl = invd * invd;
        uint4 v = *(const uint4*)&XWb[node * D + cl * 8];
        acc[0] += sl * bflo(v.x); acc[1] += sl * bfhi(v.x);
        acc[2] += sl * bflo(v.y); acc[3] += sl * bfhi(v.y);
        acc[4] += sl * bflo(v.z); acc[5] += sl * bfhi(v.z);
        acc[6] += sl * bflo(v.w); acc[7] += sl * bfhi(v.w);
    }

    for (int e = eg; e < cnt; e += 4) {
        int s = csr[start + e];
        float nrm = invd * inv[s];
        uint4 v = *(const uint4*)&XWb[s * D + cl * 8];
        acc[0] += nrm * bflo(v.x); acc[1] += nrm * bfhi(v.x);
        acc[2] += nrm * bflo(v.y); acc[3] += nrm * bfhi(v.y);
        acc[4] += nrm * bflo(v.z); acc[5] += nrm * bfhi(v.z);
        acc[6] += nrm * bflo(v.w); acc[7] += nrm * bfhi(v.w);
    }

    // reduce across the 4 edge-slot groups
    #pragma unroll
    for (int j = 0; j < 8; ++j) {
        acc[j] += __shfl_xor(acc[j], 16, 64);
        acc[j] += __shfl_xor(acc[j], 32, 64);
    }

    if (l < 16) {
        float4 v0 = make_float4(acc[0], acc[1], acc[2], acc[3]);
        float4 v1 = make_float4(acc[4], acc[5], acc[6], acc[7]);
        *(float4*)&out[node * D + cl * 8] = v0;
        *(float4*)&out[node * D + cl * 8 + 4] = v1;
    }
}

extern "C" void kernel_launch(void* const* d_in, const int* in_sizes, int n_in,
                              void* d_out, int out_size, void* d_ws, size_t ws_size,
                              hipStream_t stream) {
    const float* X = (const float*)d_in[0];
    const float* W = (const float*)d_in[1];
    const int* esrc = (const int*)d_in[2];
    const int* edst = (const int*)d_in[3];
    float* out = (float*)d_out;

    char* ws = (char*)d_ws;
    int* deg = (int*)(ws + OFF_DEG);
    int* cur = (int*)(ws + OFF_CUR);
    int* offs = (int*)(ws + OFF_OFFS);
    float* inv = (float*)(ws + OFF_INV);
    int* part = (int*)(ws + OFF_PART);
    unsigned short* Wt = (unsigned short*)(ws + OFF_WT);
    int* csr = (int*)(ws + OFF_CSR);
    unsigned short* XWb = (unsigned short*)(ws + OFF_XWB);

    hipMemsetAsync(ws + OFF_DEG, 0, OFF_OFFS - OFF_DEG, stream);

    int eb = (N_EDGES + 255) / 256;
    k_degree<<<eb, 256, 0, stream>>>(edst, deg);
    k_scan1<<<SCAN_NB, SCAN_B, 0, stream>>>(deg, part);
    k_scan2<<<1, 64, 0, stream>>>(part);
    k_scan3<<<SCAN_NB, SCAN_B, 0, stream>>>(deg, part, offs, inv);
    k_fill<<<eb, 256, 0, stream>>>(esrc, edst, offs, cur, csr);

    k_convW<<<D, D, 0, stream>>>(W, Wt);
    int gb = (N_NODES + BM - 1) / BM;   // 782
    k_gemm<<<gb, 256, 0, stream>>>(X, Wt, XWb);

    int ab = (N_NODES + 3) / 4;         // 12500
    k_agg<<<ab, 256, 0, stream>>>(XWb, csr, offs, deg, inv, out);
}

// Round 3
// 115.124 us; speedup vs baseline: 1.8318x; 1.3010x over previous
//
#include <hip/hip_runtime.h>

#define N_NODES 50000
#define N_EDGES 800000
#define D 128

typedef __attribute__((ext_vector_type(8))) short bf16x8;
typedef __attribute__((ext_vector_type(4))) float f32x4;

// ---------------- workspace layout (bytes) ----------------
static const size_t OFF_DEG  = 0;          // int[50000]
static const size_t OFF_OFFS = 200192;     // int[50000]
static const size_t OFF_INV  = 400384;     // float[50000]
static const size_t OFF_PART = 600576;     // int[49]
static const size_t OFF_WT   = 601088;     // ushort[128*128] bf16 W^T [n][k]
static const size_t OFF_SLOT = 633856;     // ushort[800000]
static const size_t OFF_CSR  = 2233856;    // ushort[800000]
static const size_t OFF_XWB  = 3833856;    // ushort[50000*128] bf16
// total: 16,633,856 bytes

#define SCAN_B 1024
#define SCAN_NB ((N_NODES + SCAN_B - 1) / SCAN_B)   // 49

__device__ __forceinline__ unsigned short f2bf(float f) {
    unsigned int u = __float_as_uint(f);
    unsigned int r = (u + 0x7fffu + ((u >> 16) & 1u)) >> 16;   // RNE
    return (unsigned short)r;
}
__device__ __forceinline__ float bflo(unsigned int u) { return __uint_as_float(u << 16); }
__device__ __forceinline__ float bfhi(unsigned int u) { return __uint_as_float(u & 0xffff0000u); }

// degree + slot assignment in ONE atomic pass
__global__ void k_degree(const int* __restrict__ dst, int* __restrict__ deg,
                         unsigned short* __restrict__ slot) {
    int e = blockIdx.x * blockDim.x + threadIdx.x;
    if (e < N_EDGES) {
        int p = atomicAdd(&deg[dst[e]], 1);
        slot[e] = (unsigned short)p;
    }
}

__global__ void k_scan1(const int* __restrict__ deg, int* __restrict__ part) {
    int t = threadIdx.x;
    int i = blockIdx.x * SCAN_B + t;
    int v = (i < N_NODES) ? deg[i] : 0;
    #pragma unroll
    for (int off = 32; off >= 1; off >>= 1) v += __shfl_down(v, off, 64);
    __shared__ int ws[16];
    int wid = t >> 6, lane = t & 63;
    if (lane == 0) ws[wid] = v;
    __syncthreads();
    if (t < 64) {
        int s = (t < 16) ? ws[t] : 0;
        #pragma unroll
        for (int off = 8; off >= 1; off >>= 1) s += __shfl_down(s, off, 64);
        if (t == 0) part[blockIdx.x] = s;
    }
}

__global__ void k_scan2(int* part) {
    int lane = threadIdx.x;  // one wave
    int orig = (lane < SCAN_NB) ? part[lane] : 0;
    int v = orig;
    #pragma unroll
    for (int d = 1; d < 64; d <<= 1) {
        int u = __shfl_up(v, d, 64);
        if (lane >= d) v += u;
    }
    if (lane < SCAN_NB) part[lane] = v - orig;  // exclusive
}

__global__ void k_scan3(const int* __restrict__ deg, const int* __restrict__ part,
                        int* __restrict__ offs, float* __restrict__ inv) {
    int t = threadIdx.x;
    int i = blockIdx.x * SCAN_B + t;
    int v = (i < N_NODES) ? deg[i] : 0;
    int s = v;
    #pragma unroll
    for (int d = 1; d < 64; d <<= 1) {
        int u = __shfl_up(s, d, 64);
        if ((t & 63) >= d) s += u;
    }
    __shared__ int wsum[16];
    if ((t & 63) == 63) wsum[t >> 6] = s;
    __syncthreads();
    if (t < 64) {
        int val = (t < 16) ? wsum[t] : 0;
        int sc = val;
        #pragma unroll
        for (int d = 1; d < 16; d <<= 1) {
            int u = __shfl_up(sc, d, 64);
            if (t >= d) sc += u;
        }
        if (t < 16) wsum[t] = sc - val;  // exclusive over waves
    }
    __syncthreads();
    if (i < N_NODES) {
        int excl = s - v + wsum[t >> 6] + part[blockIdx.x];
        offs[i] = excl;
        inv[i] = rsqrtf((float)v + 1.0f);
    }
}

// atomic-free CSR fill: 2-byte scatter
__global__ void k_fill(const int* __restrict__ src, const int* __restrict__ dst,
                       const int* __restrict__ offs,
                       const unsigned short* __restrict__ slot,
                       unsigned short* __restrict__ csr) {
    int e = blockIdx.x * blockDim.x + threadIdx.x;
    if (e < N_EDGES) {
        csr[offs[dst[e]] + (int)slot[e]] = (unsigned short)src[e];
    }
}

// ---- Wt[n][k] = bf16(W[k][n]) ----
__global__ void k_convW(const float* __restrict__ W, unsigned short* __restrict__ Wt) {
    int n = blockIdx.x;
    int k = threadIdx.x;
    Wt[n * D + k] = f2bf(W[k * D + n]);
}

// ---------------- XW(bf16) = X @ W via MFMA 16x16x32 bf16 ----------------
#define BM 64
__global__ __launch_bounds__(256) void k_gemm(const float* __restrict__ X,
                                              const unsigned short* __restrict__ Wt,
                                              unsigned short* __restrict__ XWb) {
    __shared__ unsigned short sA[BM * D];    // 16KB swizzled [row][k]
    __shared__ unsigned short sB[D * D];     // 32KB swizzled [n][k]
    int t = threadIdx.x;
    int r0 = blockIdx.x * BM;

    #pragma unroll
    for (int p = 0; p < 8; ++p) {
        int e = p * 2048 + t * 8;
        int n = e >> 7, k = e & 127;
        uint4 v = *(const uint4*)&Wt[e];
        int idx = n * D + (((k >> 3) ^ (n & 7)) << 3);
        *(uint4*)&sB[idx] = v;
    }
    #pragma unroll
    for (int p = 0; p < 8; ++p) {
        int e = p * 1024 + t * 4;
        int r = e >> 7, c = e & 127;
        int row = r0 + r;
        float4 xv = make_float4(0.f, 0.f, 0.f, 0.f);
        if (row < N_NODES) xv = *(const float4*)&X[row * D + c];
        ushort4 bv;
        bv.x = f2bf(xv.x); bv.y = f2bf(xv.y); bv.z = f2bf(xv.z); bv.w = f2bf(xv.w);
        int idx = r * D + (((c >> 3) ^ (r & 7)) << 3) + (c & 7);
        *(ushort4*)&sA[idx] = bv;
    }
    __syncthreads();

    int w = t >> 6, l = t & 63;
    int arow = w * 16 + (l & 15);
    f32x4 acc[8];
    #pragma unroll
    for (int i = 0; i < 8; ++i) acc[i] = (f32x4){0.f, 0.f, 0.f, 0.f};

    #pragma unroll
    for (int kk = 0; kk < 4; ++kk) {
        int g = kk * 4 + (l >> 4);
        bf16x8 a = *(bf16x8*)&sA[arow * D + ((g ^ (arow & 7)) << 3)];
        #pragma unroll
        for (int nt = 0; nt < 8; ++nt) {
            int nrow = nt * 16 + (l & 15);
            bf16x8 b = *(bf16x8*)&sB[nrow * D + ((g ^ (nrow & 7)) << 3)];
            acc[nt] = __builtin_amdgcn_mfma_f32_16x16x32_bf16(a, b, acc[nt], 0, 0, 0);
        }
    }

    #pragma unroll
    for (int nt = 0; nt < 8; ++nt) {
        #pragma unroll
        for (int r = 0; r < 4; ++r) {
            int m = r0 + w * 16 + (l >> 4) * 4 + r;
            if (m < N_NODES) XWb[m * D + nt * 16 + (l & 15)] = f2bf(acc[nt][r]);
        }
    }
}

// ---------------- aggregate (bf16 gather, f32 out) ----------------
// One wave per node; 4 edge-slots x 16 lanes; edge loop unrolled x2 for MLP.
__global__ __launch_bounds__(256) void k_agg(const unsigned short* __restrict__ XWb,
                                             const unsigned short* __restrict__ csr,
                                             const int* __restrict__ offs,
                                             const int* __restrict__ deg,
                                             const float* __restrict__ inv,
                                             float* __restrict__ out) {
    int node = blockIdx.x * 4 + (threadIdx.x >> 6);
    if (node >= N_NODES) return;
    int l = threadIdx.x & 63;
    int eg = l >> 4;
    int cl = l & 15;

    int start = offs[node];
    int cnt = deg[node];
    float invd = inv[node];

    float acc[8];
    #pragma unroll
    for (int j = 0; j < 8; ++j) acc[j] = 0.f;

    if (eg == 0) {
        float sl = invd * invd;
        uint4 v = *(const uint4*)&XWb[node * D + cl * 8];
        acc[0] += sl * bflo(v.x); acc[1] += sl * bfhi(v.x);
        acc[2] += sl * bflo(v.y); acc[3] += sl * bfhi(v.y);
        acc[4] += sl * bflo(v.z); acc[5] += sl * bfhi(v.z);
        acc[6] += sl * bflo(v.w); acc[7] += sl * bfhi(v.w);
    }

    for (int e = eg; e < cnt; e += 8) {
        int s0 = (int)csr[start + e];
        uint4 v0 = *(const uint4*)&XWb[s0 * D + cl * 8];
        float n0 = invd * inv[s0];
        int e1 = e + 4;
        int ok1 = (e1 < cnt);
        int s1 = ok1 ? (int)csr[start + e1] : s0;
        uint4 v1 = *(const uint4*)&XWb[s1 * D + cl * 8];
        float n1 = ok1 ? invd * inv[s1] : 0.f;

        acc[0] += n0 * bflo(v0.x); acc[1] += n0 * bfhi(v0.x);
        acc[2] += n0 * bflo(v0.y); acc[3] += n0 * bfhi(v0.y);
        acc[4] += n0 * bflo(v0.z); acc[5] += n0 * bfhi(v0.z);
        acc[6] += n0 * bflo(v0.w); acc[7] += n0 * bfhi(v0.w);
        acc[0] += n1 * bflo(v1.x); acc[1] += n1 * bfhi(v1.x);
        acc[2] += n1 * bflo(v1.y); acc[3] += n1 * bfhi(v1.y);
        acc[4] += n1 * bflo(v1.z); acc[5] += n1 * bfhi(v1.z);
        acc[6] += n1 * bflo(v1.w); acc[7] += n1 * bfhi(v1.w);
    }

    #pragma unroll
    for (int j = 0; j < 8; ++j) {
        acc[j] += __shfl_xor(acc[j], 16, 64);
        acc[j] += __shfl_xor(acc[j], 32, 64);
    }

    if (l < 16) {
        float4 v0 = make_float4(acc[0], acc[1], acc[2], acc[3]);
        float4 v1 = make_float4(acc[4], acc[5], acc[6], acc[7]);
        *(float4*)&out[node * D + cl * 8] = v0;
        *(float4*)&out[node * D + cl * 8 + 4] = v1;
    }
}

extern "C" void kernel_launch(void* const* d_in, const int* in_sizes, int n_in,
                              void* d_out, int out_size, void* d_ws, size_t ws_size,
                              hipStream_t stream) {
    const float* X = (const float*)d_in[0];
    const float* W = (const float*)d_in[1];
    const int* esrc = (const int*)d_in[2];
    const int* edst = (const int*)d_in[3];
    float* out = (float*)d_out;

    char* ws = (char*)d_ws;
    int* deg = (int*)(ws + OFF_DEG);
    int* offs = (int*)(ws + OFF_OFFS);
    float* inv = (float*)(ws + OFF_INV);
    int* part = (int*)(ws + OFF_PART);
    unsigned short* Wt = (unsigned short*)(ws + OFF_WT);
    unsigned short* slot = (unsigned short*)(ws + OFF_SLOT);
    unsigned short* csr = (unsigned short*)(ws + OFF_CSR);
    unsigned short* XWb = (unsigned short*)(ws + OFF_XWB);

    hipMemsetAsync(ws + OFF_DEG, 0, OFF_OFFS - OFF_DEG, stream);

    int eb = (N_EDGES + 255) / 256;
    k_degree<<<eb, 256, 0, stream>>>(edst, deg, slot);
    k_scan1<<<SCAN_NB, SCAN_B, 0, stream>>>(deg, part);
    k_scan2<<<1, 64, 0, stream>>>(part);
    k_scan3<<<SCAN_NB, SCAN_B, 0, stream>>>(deg, part, offs, inv);
    k_fill<<<eb, 256, 0, stream>>>(esrc, edst, offs, slot, csr);

    k_convW<<<D, D, 0, stream>>>(W, Wt);
    int gb = (N_NODES + BM - 1) / BM;   // 782
    k_gemm<<<gb, 256, 0, stream>>>(X, Wt, XWb);

    int ab = (N_NODES + 3) / 4;         // 12500
    k_agg<<<ab, 256, 0, stream>>>(XWb, csr, offs, deg, inv, out);
}

// Round 4
// 110.942 us; speedup vs baseline: 1.9009x; 1.0377x over previous
//
#include <hip/hip_runtime.h>

#define N_NODES 50000
#define N_EDGES 800000
#define D 128

typedef __attribute__((ext_vector_type(8))) short bf16x8;
typedef __attribute__((ext_vector_type(4))) float f32x4;

// ---------------- workspace layout (bytes) ----------------
static const size_t OFF_DEG  = 0;          // int[50000]
static const size_t OFF_OFFS = 200192;     // int[50000]
static const size_t OFF_INV  = 400384;     // float[50000]
static const size_t OFF_PART = 600576;     // int[49]
static const size_t OFF_WT   = 601088;     // ushort[128*128] bf16 W^T [n][k]
static const size_t OFF_SLOT = 633856;     // ushort[800000]
static const size_t OFF_CSR  = 2233856;    // ushort[800000]
static const size_t OFF_XWB  = 3833856;    // ushort[50000*128] bf16
// total: 16,633,856 bytes

#define SCAN_B 1024
#define SCAN_NB ((N_NODES + SCAN_B - 1) / SCAN_B)   // 49

__device__ __forceinline__ unsigned short f2bf(float f) {
    unsigned int u = __float_as_uint(f);
    unsigned int r = (u + 0x7fffu + ((u >> 16) & 1u)) >> 16;   // RNE
    return (unsigned short)r;
}
__device__ __forceinline__ float bflo(unsigned int u) { return __uint_as_float(u << 16); }
__device__ __forceinline__ float bfhi(unsigned int u) { return __uint_as_float(u & 0xffff0000u); }

// zero deg[] — replaces the pathologically slow graph-captured hipMemsetAsync
__global__ void k_zero(int4* __restrict__ p) {
    int i = blockIdx.x * blockDim.x + threadIdx.x;   // 12500 int4
    if (i < (N_NODES / 4)) p[i] = make_int4(0, 0, 0, 0);
}

// degree + slot assignment in ONE atomic pass
__global__ void k_degree(const int* __restrict__ dst, int* __restrict__ deg,
                         unsigned short* __restrict__ slot) {
    int e = blockIdx.x * blockDim.x + threadIdx.x;
    if (e < N_EDGES) {
        int p = atomicAdd(&deg[dst[e]], 1);
        slot[e] = (unsigned short)p;
    }
}

__global__ void k_scan1(const int* __restrict__ deg, int* __restrict__ part) {
    int t = threadIdx.x;
    int i = blockIdx.x * SCAN_B + t;
    int v = (i < N_NODES) ? deg[i] : 0;
    #pragma unroll
    for (int off = 32; off >= 1; off >>= 1) v += __shfl_down(v, off, 64);
    __shared__ int ws[16];
    int wid = t >> 6, lane = t & 63;
    if (lane == 0) ws[wid] = v;
    __syncthreads();
    if (t < 64) {
        int s = (t < 16) ? ws[t] : 0;
        #pragma unroll
        for (int off = 8; off >= 1; off >>= 1) s += __shfl_down(s, off, 64);
        if (t == 0) part[blockIdx.x] = s;
    }
}

__global__ void k_scan2(int* part) {
    int lane = threadIdx.x;  // one wave
    int orig = (lane < SCAN_NB) ? part[lane] : 0;
    int v = orig;
    #pragma unroll
    for (int d = 1; d < 64; d <<= 1) {
        int u = __shfl_up(v, d, 64);
        if (lane >= d) v += u;
    }
    if (lane < SCAN_NB) part[lane] = v - orig;  // exclusive
}

__global__ void k_scan3(const int* __restrict__ deg, const int* __restrict__ part,
                        int* __restrict__ offs, float* __restrict__ inv) {
    int t = threadIdx.x;
    int i = blockIdx.x * SCAN_B + t;
    int v = (i < N_NODES) ? deg[i] : 0;
    int s = v;
    #pragma unroll
    for (int d = 1; d < 64; d <<= 1) {
        int u = __shfl_up(s, d, 64);
        if ((t & 63) >= d) s += u;
    }
    __shared__ int wsum[16];
    if ((t & 63) == 63) wsum[t >> 6] = s;
    __syncthreads();
    if (t < 64) {
        int val = (t < 16) ? wsum[t] : 0;
        int sc = val;
        #pragma unroll
        for (int d = 1; d < 16; d <<= 1) {
            int u = __shfl_up(sc, d, 64);
            if (t >= d) sc += u;
        }
        if (t < 16) wsum[t] = sc - val;  // exclusive over waves
    }
    __syncthreads();
    if (i < N_NODES) {
        int excl = s - v + wsum[t >> 6] + part[blockIdx.x];
        offs[i] = excl;
        inv[i] = rsqrtf((float)v + 1.0f);
    }
}

// atomic-free CSR fill: 2-byte scatter
__global__ void k_fill(const int* __restrict__ src, const int* __restrict__ dst,
                       const int* __restrict__ offs,
                       const unsigned short* __restrict__ slot,
                       unsigned short* __restrict__ csr) {
    int e = blockIdx.x * blockDim.x + threadIdx.x;
    if (e < N_EDGES) {
        csr[offs[dst[e]] + (int)slot[e]] = (unsigned short)src[e];
    }
}

// ---- Wt[n][k] = bf16(W[k][n]) ----
__global__ void k_convW(const float* __restrict__ W, unsigned short* __restrict__ Wt) {
    int n = blockIdx.x;
    int k = threadIdx.x;
    Wt[n * D + k] = f2bf(W[k * D + n]);
}

// ---------------- XW(bf16) = X @ W via MFMA 16x16x32 bf16 ----------------
#define BM 64
__global__ __launch_bounds__(256) void k_gemm(const float* __restrict__ X,
                                              const unsigned short* __restrict__ Wt,
                                              unsigned short* __restrict__ XWb) {
    __shared__ unsigned short sA[BM * D];    // 16KB swizzled [row][k]
    __shared__ unsigned short sB[D * D];     // 32KB swizzled [n][k]
    int t = threadIdx.x;
    int r0 = blockIdx.x * BM;

    #pragma unroll
    for (int p = 0; p < 8; ++p) {
        int e = p * 2048 + t * 8;
        int n = e >> 7, k = e & 127;
        uint4 v = *(const uint4*)&Wt[e];
        int idx = n * D + (((k >> 3) ^ (n & 7)) << 3);
        *(uint4*)&sB[idx] = v;
    }
    #pragma unroll
    for (int p = 0; p < 8; ++p) {
        int e = p * 1024 + t * 4;
        int r = e >> 7, c = e & 127;
        int row = r0 + r;
        float4 xv = make_float4(0.f, 0.f, 0.f, 0.f);
        if (row < N_NODES) xv = *(const float4*)&X[row * D + c];
        ushort4 bv;
        bv.x = f2bf(xv.x); bv.y = f2bf(xv.y); bv.z = f2bf(xv.z); bv.w = f2bf(xv.w);
        int idx = r * D + (((c >> 3) ^ (r & 7)) << 3) + (c & 7);
        *(ushort4*)&sA[idx] = bv;
    }
    __syncthreads();

    int w = t >> 6, l = t & 63;
    int arow = w * 16 + (l & 15);
    f32x4 acc[8];
    #pragma unroll
    for (int i = 0; i < 8; ++i) acc[i] = (f32x4){0.f, 0.f, 0.f, 0.f};

    #pragma unroll
    for (int kk = 0; kk < 4; ++kk) {
        int g = kk * 4 + (l >> 4);
        bf16x8 a = *(bf16x8*)&sA[arow * D + ((g ^ (arow & 7)) << 3)];
        #pragma unroll
        for (int nt = 0; nt < 8; ++nt) {
            int nrow = nt * 16 + (l & 15);
            bf16x8 b = *(bf16x8*)&sB[nrow * D + ((g ^ (nrow & 7)) << 3)];
            acc[nt] = __builtin_amdgcn_mfma_f32_16x16x32_bf16(a, b, acc[nt], 0, 0, 0);
        }
    }

    #pragma unroll
    for (int nt = 0; nt < 8; ++nt) {
        #pragma unroll
        for (int r = 0; r < 4; ++r) {
            int m = r0 + w * 16 + (l >> 4) * 4 + r;
            if (m < N_NODES) XWb[m * D + nt * 16 + (l & 15)] = f2bf(acc[nt][r]);
        }
    }
}

// ---------------- aggregate (bf16 gather, f32 out) ----------------
// One wave per node; 4 edge-slots x 16 lanes; 4-deep gather pipeline.
__global__ __launch_bounds__(256) void k_agg(const unsigned short* __restrict__ XWb,
                                             const unsigned short* __restrict__ csr,
                                             const int* __restrict__ offs,
                                             const int* __restrict__ deg,
                                             const float* __restrict__ inv,
                                             float* __restrict__ out) {
    int node = blockIdx.x * 4 + (threadIdx.x >> 6);
    if (node >= N_NODES) return;
    int l = threadIdx.x & 63;
    int eg = l >> 4;
    int cl = l & 15;

    int start = offs[node];
    int cnt = deg[node];
    float invd = inv[node];

    float acc[8];
    #pragma unroll
    for (int j = 0; j < 8; ++j) acc[j] = 0.f;

    if (eg == 0) {
        float sl = invd * invd;
        uint4 v = *(const uint4*)&XWb[node * D + cl * 8];
        acc[0] += sl * bflo(v.x); acc[1] += sl * bfhi(v.x);
        acc[2] += sl * bflo(v.y); acc[3] += sl * bfhi(v.y);
        acc[4] += sl * bflo(v.z); acc[5] += sl * bfhi(v.z);
        acc[6] += sl * bflo(v.w); acc[7] += sl * bfhi(v.w);
    }

    for (int e = eg; e < cnt; e += 16) {
        int s[4];
        #pragma unroll
        for (int u = 0; u < 4; ++u) {
            int ee = e + u * 4;
            s[u] = (ee < cnt) ? (int)csr[start + ee] : -1;
        }
        uint4 v[4];
        float nn[4];
        #pragma unroll
        for (int u = 0; u < 4; ++u) {
            int si = (s[u] >= 0) ? s[u] : s[0];
            v[u] = *(const uint4*)&XWb[si * D + cl * 8];
            nn[u] = (s[u] >= 0) ? invd * inv[si] : 0.f;
        }
        #pragma unroll
        for (int u = 0; u < 4; ++u) {
            float n = nn[u];
            acc[0] += n * bflo(v[u].x); acc[1] += n * bfhi(v[u].x);
            acc[2] += n * bflo(v[u].y); acc[3] += n * bfhi(v[u].y);
            acc[4] += n * bflo(v[u].z); acc[5] += n * bfhi(v[u].z);
            acc[6] += n * bflo(v[u].w); acc[7] += n * bfhi(v[u].w);
        }
    }

    #pragma unroll
    for (int j = 0; j < 8; ++j) {
        acc[j] += __shfl_xor(acc[j], 16, 64);
        acc[j] += __shfl_xor(acc[j], 32, 64);
    }

    if (l < 16) {
        float4 v0 = make_float4(acc[0], acc[1], acc[2], acc[3]);
        float4 v1 = make_float4(acc[4], acc[5], acc[6], acc[7]);
        *(float4*)&out[node * D + cl * 8] = v0;
        *(float4*)&out[node * D + cl * 8 + 4] = v1;
    }
}

extern "C" void kernel_launch(void* const* d_in, const int* in_sizes, int n_in,
                              void* d_out, int out_size, void* d_ws, size_t ws_size,
                              hipStream_t stream) {
    const float* X = (const float*)d_in[0];
    const float* W = (const float*)d_in[1];
    const int* esrc = (const int*)d_in[2];
    const int* edst = (const int*)d_in[3];
    float* out = (float*)d_out;

    char* ws = (char*)d_ws;
    int* deg = (int*)(ws + OFF_DEG);
    int* offs = (int*)(ws + OFF_OFFS);
    float* inv = (float*)(ws + OFF_INV);
    int* part = (int*)(ws + OFF_PART);
    unsigned short* Wt = (unsigned short*)(ws + OFF_WT);
    unsigned short* slot = (unsigned short*)(ws + OFF_SLOT);
    unsigned short* csr = (unsigned short*)(ws + OFF_CSR);
    unsigned short* XWb = (unsigned short*)(ws + OFF_XWB);

    k_zero<<<(N_NODES / 4 + 255) / 256, 256, 0, stream>>>((int4*)deg);

    int eb = (N_EDGES + 255) / 256;
    k_degree<<<eb, 256, 0, stream>>>(edst, deg, slot);
    k_scan1<<<SCAN_NB, SCAN_B, 0, stream>>>(deg, part);
    k_scan2<<<1, 64, 0, stream>>>(part);
    k_scan3<<<SCAN_NB, SCAN_B, 0, stream>>>(deg, part, offs, inv);
    k_fill<<<eb, 256, 0, stream>>>(esrc, edst, offs, slot, csr);

    k_convW<<<D, D, 0, stream>>>(W, Wt);
    int gb = (N_NODES + BM - 1) / BM;   // 782
    k_gemm<<<gb, 256, 0, stream>>>(X, Wt, XWb);

    int ab = (N_NODES + 3) / 4;         // 12500
    k_agg<<<ab, 256, 0, stream>>>(XWb, csr, offs, deg, inv, out);
}

// Round 5
// 102.115 us; speedup vs baseline: 2.0652x; 1.0864x over previous
//
#include <hip/hip_runtime.h>

#define N_NODES 50000
#define N_EDGES 800000
#define D 128

typedef __attribute__((ext_vector_type(8))) short bf16x8;
typedef __attribute__((ext_vector_type(4))) float f32x4;

// ---------------- workspace layout (bytes) ----------------
static const size_t OFF_DEG  = 0;          // int[50000]            (zeroed)
static const size_t OFF_FLAG = 200000;     // int[49] lookback flags (zeroed)
// zero region = [0, 200256) = 12516 int4
static const size_t OFF_PART = 200448;     // int[49] block totals (gated by flags)
static const size_t OFF_OFFS = 200704;     // int[50000]
static const size_t OFF_INV  = 400896;     // float[50000]
static const size_t OFF_WT   = 601088;     // ushort[128*128] bf16 W^T [n][k]
static const size_t OFF_SLOT = 633856;     // ushort[800000]
static const size_t OFF_CSR  = 2233856;    // ushort[800000]
static const size_t OFF_XWB  = 3833856;    // ushort[50000*128] bf16
// total: 16,633,856 bytes

#define SCAN_B 1024
#define SCAN_NB ((N_NODES + SCAN_B - 1) / SCAN_B)   // 49
#define BM 64
#define NB_GEMM ((N_NODES + BM - 1) / BM)           // 782
#define NB_DEG  ((N_EDGES + 255) / 256)             // 3125

__device__ __forceinline__ unsigned short f2bf(float f) {
    unsigned int u = __float_as_uint(f);
    unsigned int r = (u + 0x7fffu + ((u >> 16) & 1u)) >> 16;   // RNE
    return (unsigned short)r;
}
__device__ __forceinline__ float bflo(unsigned int u) { return __uint_as_float(u << 16); }
__device__ __forceinline__ float bfhi(unsigned int u) { return __uint_as_float(u & 0xffff0000u); }

// ---- init: zero deg+flags, convert Wt[n][k] = bf16(W[k][n]) ----
__global__ void k_init(int4* __restrict__ zreg, const float* __restrict__ W,
                       unsigned short* __restrict__ Wt) {
    int bid = blockIdx.x, t = threadIdx.x;
    if (bid < 49) {
        int i = bid * 256 + t;
        if (i < 12516) zreg[i] = make_int4(0, 0, 0, 0);
    } else {
        int idx = (bid - 49) * 256 + t;   // 0..16383
        int n = idx >> 7, k = idx & 127;
        Wt[n * D + k] = f2bf(W[k * D + n]);
    }
}

// ---- fused: GEMM blocks (every 4th bid) + degree/slot blocks ----
// gemm: XW(bf16) = X @ W via MFMA 16x16x32, XOR-swizzled LDS
// degree: deg[dst]++ with slot capture (one atomic pass)
__global__ __launch_bounds__(256) void k_dg(const float* __restrict__ X,
                                            const unsigned short* __restrict__ Wt,
                                            unsigned short* __restrict__ XWb,
                                            const int* __restrict__ dst,
                                            int* __restrict__ deg,
                                            unsigned short* __restrict__ slot) {
    __shared__ unsigned short sA[BM * D];    // 16KB swizzled [row][k]
    __shared__ unsigned short sB[D * D];     // 32KB swizzled [n][k]
    int bid = blockIdx.x;
    int t = threadIdx.x;
    bool isg = ((bid & 3) == 0) && ((bid >> 2) < NB_GEMM);

    if (!isg) {
        int did = (bid < NB_GEMM * 4) ? (bid - (bid >> 2) - 1) : (bid - NB_GEMM);
        int e = did * 256 + t;
        if (e < N_EDGES) {
            int p = atomicAdd(&deg[dst[e]], 1);
            slot[e] = (unsigned short)p;
        }
        return;
    }

    int r0 = (bid >> 2) * BM;

    #pragma unroll
    for (int p = 0; p < 8; ++p) {
        int e = p * 2048 + t * 8;
        int n = e >> 7, k = e & 127;
        uint4 v = *(const uint4*)&Wt[e];
        int idx = n * D + (((k >> 3) ^ (n & 7)) << 3);
        *(uint4*)&sB[idx] = v;
    }
    #pragma unroll
    for (int p = 0; p < 8; ++p) {
        int e = p * 1024 + t * 4;
        int r = e >> 7, c = e & 127;
        int row = r0 + r;
        float4 xv = make_float4(0.f, 0.f, 0.f, 0.f);
        if (row < N_NODES) xv = *(const float4*)&X[row * D + c];
        ushort4 bv;
        bv.x = f2bf(xv.x); bv.y = f2bf(xv.y); bv.z = f2bf(xv.z); bv.w = f2bf(xv.w);
        int idx = r * D + (((c >> 3) ^ (r & 7)) << 3) + (c & 7);
        *(ushort4*)&sA[idx] = bv;
    }
    __syncthreads();

    int w = t >> 6, l = t & 63;
    int arow = w * 16 + (l & 15);
    f32x4 acc[8];
    #pragma unroll
    for (int i = 0; i < 8; ++i) acc[i] = (f32x4){0.f, 0.f, 0.f, 0.f};

    #pragma unroll
    for (int kk = 0; kk < 4; ++kk) {
        int g = kk * 4 + (l >> 4);
        bf16x8 a = *(bf16x8*)&sA[arow * D + ((g ^ (arow & 7)) << 3)];
        #pragma unroll
        for (int nt = 0; nt < 8; ++nt) {
            int nrow = nt * 16 + (l & 15);
            bf16x8 b = *(bf16x8*)&sB[nrow * D + ((g ^ (nrow & 7)) << 3)];
            acc[nt] = __builtin_amdgcn_mfma_f32_16x16x32_bf16(a, b, acc[nt], 0, 0, 0);
        }
    }

    #pragma unroll
    for (int nt = 0; nt < 8; ++nt) {
        #pragma unroll
        for (int r = 0; r < 4; ++r) {
            int m = r0 + w * 16 + (l >> 4) * 4 + r;
            if (m < N_NODES) XWb[m * D + nt * 16 + (l & 15)] = f2bf(acc[nt][r]);
        }
    }
}

// ---- single-launch scan (decoupled lookback, 49 co-resident blocks) ----
__global__ __launch_bounds__(1024) void k_scan(const int* __restrict__ deg,
                                               int* __restrict__ part,
                                               int* __restrict__ flag,
                                               int* __restrict__ offs,
                                               float* __restrict__ inv) {
    int b = blockIdx.x;
    int t = threadIdx.x;
    int i = b * SCAN_B + t;
    int v = (i < N_NODES) ? deg[i] : 0;
    int s = v;
    #pragma unroll
    for (int d = 1; d < 64; d <<= 1) {
        int u = __shfl_up(s, d, 64);
        if ((t & 63) >= d) s += u;
    }
    __shared__ int wsum[16];
    __shared__ int s_prefix;
    if ((t & 63) == 63) wsum[t >> 6] = s;
    __syncthreads();
    if (t < 64) {
        int val = (t < 16) ? wsum[t] : 0;
        int sc = val;
        #pragma unroll
        for (int d = 1; d < 16; d <<= 1) {
            int u = __shfl_up(sc, d, 64);
            if (t >= d) sc += u;
        }
        if (t < 16) wsum[t] = sc - val;     // exclusive over waves
        int total = __shfl(sc, 15, 64);     // block total
        if (t == 0) {
            part[b] = total;
            __threadfence();
            atomicExch(&flag[b], 1);
        }
        int pv = 0;
        if (t < b) {
            while (atomicAdd(&flag[t], 0) == 0) { }
        }
        __threadfence();
        if (t < b) pv = atomicAdd(&part[t], 0);
        #pragma unroll
        for (int off = 32; off >= 1; off >>= 1) pv += __shfl_down(pv, off, 64);
        if (t == 0) s_prefix = pv;
    }
    __syncthreads();
    if (i < N_NODES) {
        offs[i] = s - v + wsum[t >> 6] + s_prefix;
        inv[i] = rsqrtf((float)v + 1.0f);
    }
}

// ---- atomic-free CSR fill: 2-byte scatter ----
__global__ void k_fill(const int* __restrict__ src, const int* __restrict__ dst,
                       const int* __restrict__ offs,
                       const unsigned short* __restrict__ slot,
                       unsigned short* __restrict__ csr) {
    int e = blockIdx.x * blockDim.x + threadIdx.x;
    if (e < N_EDGES) {
        csr[offs[dst[e]] + (int)slot[e]] = (unsigned short)src[e];
    }
}

// ---- aggregate (bf16 gather, f32 out), 4-deep gather pipeline ----
__global__ __launch_bounds__(256) void k_agg(const unsigned short* __restrict__ XWb,
                                             const unsigned short* __restrict__ csr,
                                             const int* __restrict__ offs,
                                             const int* __restrict__ deg,
                                             const float* __restrict__ inv,
                                             float* __restrict__ out) {
    int node = blockIdx.x * 4 + (threadIdx.x >> 6);
    if (node >= N_NODES) return;
    int l = threadIdx.x & 63;
    int eg = l >> 4;
    int cl = l & 15;

    int start = offs[node];
    int cnt = deg[node];
    float invd = inv[node];

    float acc[8];
    #pragma unroll
    for (int j = 0; j < 8; ++j) acc[j] = 0.f;

    if (eg == 0) {
        float sl = invd * invd;
        uint4 v = *(const uint4*)&XWb[node * D + cl * 8];
        acc[0] += sl * bflo(v.x); acc[1] += sl * bfhi(v.x);
        acc[2] += sl * bflo(v.y); acc[3] += sl * bfhi(v.y);
        acc[4] += sl * bflo(v.z); acc[5] += sl * bfhi(v.z);
        acc[6] += sl * bflo(v.w); acc[7] += sl * bfhi(v.w);
    }

    for (int e = eg; e < cnt; e += 16) {
        int s[4];
        #pragma unroll
        for (int u = 0; u < 4; ++u) {
            int ee = e + u * 4;
            s[u] = (ee < cnt) ? (int)csr[start + ee] : -1;
        }
        uint4 v[4];
        float nn[4];
        #pragma unroll
        for (int u = 0; u < 4; ++u) {
            int si = (s[u] >= 0) ? s[u] : s[0];
            v[u] = *(const uint4*)&XWb[si * D + cl * 8];
            nn[u] = (s[u] >= 0) ? invd * inv[si] : 0.f;
        }
        #pragma unroll
        for (int u = 0; u < 4; ++u) {
            float n = nn[u];
            acc[0] += n * bflo(v[u].x); acc[1] += n * bfhi(v[u].x);
            acc[2] += n * bflo(v[u].y); acc[3] += n * bfhi(v[u].y);
            acc[4] += n * bflo(v[u].z); acc[5] += n * bfhi(v[u].z);
            acc[6] += n * bflo(v[u].w); acc[7] += n * bfhi(v[u].w);
        }
    }

    #pragma unroll
    for (int j = 0; j < 8; ++j) {
        acc[j] += __shfl_xor(acc[j], 16, 64);
        acc[j] += __shfl_xor(acc[j], 32, 64);
    }

    if (l < 16) {
        float4 v0 = make_float4(acc[0], acc[1], acc[2], acc[3]);
        float4 v1 = make_float4(acc[4], acc[5], acc[6], acc[7]);
        *(float4*)&out[node * D + cl * 8] = v0;
        *(float4*)&out[node * D + cl * 8 + 4] = v1;
    }
}

extern "C" void kernel_launch(void* const* d_in, const int* in_sizes, int n_in,
                              void* d_out, int out_size, void* d_ws, size_t ws_size,
                              hipStream_t stream) {
    const float* X = (const float*)d_in[0];
    const float* W = (const float*)d_in[1];
    const int* esrc = (const int*)d_in[2];
    const int* edst = (const int*)d_in[3];
    float* out = (float*)d_out;

    char* ws = (char*)d_ws;
    int* deg = (int*)(ws + OFF_DEG);
    int* flag = (int*)(ws + OFF_FLAG);
    int* part = (int*)(ws + OFF_PART);
    int* offs = (int*)(ws + OFF_OFFS);
    float* inv = (float*)(ws + OFF_INV);
    unsigned short* Wt = (unsigned short*)(ws + OFF_WT);
    unsigned short* slot = (unsigned short*)(ws + OFF_SLOT);
    unsigned short* csr = (unsigned short*)(ws + OFF_CSR);
    unsigned short* XWb = (unsigned short*)(ws + OFF_XWB);

    k_init<<<113, 256, 0, stream>>>((int4*)(ws + OFF_DEG), W, Wt);
    k_dg<<<NB_GEMM * 4 + (NB_DEG - NB_GEMM * 3), 256, 0, stream>>>(X, Wt, XWb, edst, deg, slot);
    k_scan<<<SCAN_NB, SCAN_B, 0, stream>>>(deg, part, flag, offs, inv);
    k_fill<<<NB_DEG, 256, 0, stream>>>(esrc, edst, offs, slot, csr);
    k_agg<<<(N_NODES + 3) / 4, 256, 0, stream>>>(XWb, csr, offs, deg, inv, out);
}